// Round 11
// baseline (115.352 us; speedup 1.0000x reference)
//
#include <hip/hip_runtime.h>
#include <math.h>

#define D      256
#define NSEC   10
#define EPS    1e-6f
#define SLICE  0.1f

// ws float layout
#define WS_SUMS 0                      // [0,2560) per-sector sums
#define WS_CNT  (NSEC * D)             // [2560,2570) per-sector counts
#define WS_PART (NSEC * D + NSEC)      // [2570,2826) per-block distance partials (256)
#define WS_WARM (NSEC * D + NSEC + 256)// [2826,3850) warm-probe dummy outputs (1024)
#define WS_ZERO_FLOATS (NSEC * D + NSEC)

#define DIST_BLOCKS 256

__global__ void k_zero(float* __restrict__ ws) {
    int i = blockIdx.x * blockDim.x + threadIdx.x;
    if (i < WS_ZERO_FLOATS) ws[i] = 0.f;
}

__global__ __launch_bounds__(256) void k_sums(const float* __restrict__ emb,
                                              const int* __restrict__ sec,
                                              float* __restrict__ ws, int nrows) {
    const int lane = threadIdx.x & 63;
    const int wid  = threadIdx.x >> 6;          // 0..3
    const int gw   = blockIdx.x * 4 + wid;      // global wave id
    const int nw   = gridDim.x * 4;

    float4 acc[NSEC];
    float  cnt[NSEC];
#pragma unroll
    for (int s = 0; s < NSEC; ++s) { acc[s] = make_float4(0.f, 0.f, 0.f, 0.f); cnt[s] = 0.f; }

    const float* ep = emb + (size_t)lane * 4;

    auto accum = [&](int sv, float4 v) {
        const int s = __builtin_amdgcn_readfirstlane(sv);  // wave-uniform -> SGPR branch
#pragma unroll
        for (int ss = 0; ss < NSEC; ++ss) {
            if (s == ss) {   // scalar branch; acc index compile-time constant
                acc[ss].x += v.x; acc[ss].y += v.y; acc[ss].z += v.z; acc[ss].w += v.w;
                cnt[ss] += 1.f;
            }
        }
    };

    int r = gw;
    for (; r + 3 * nw < nrows; r += 4 * nw) {
        const int s0 = sec[r];
        const int s1 = sec[r + nw];
        const int s2 = sec[r + 2 * nw];
        const int s3 = sec[r + 3 * nw];
        const float4 v0 = *reinterpret_cast<const float4*>(ep + (size_t)r * D);
        const float4 v1 = *reinterpret_cast<const float4*>(ep + (size_t)(r + nw) * D);
        const float4 v2 = *reinterpret_cast<const float4*>(ep + (size_t)(r + 2 * nw) * D);
        const float4 v3 = *reinterpret_cast<const float4*>(ep + (size_t)(r + 3 * nw) * D);
        accum(s0, v0); accum(s1, v1); accum(s2, v2); accum(s3, v3);
    }
    for (; r < nrows; r += nw)
        accum(sec[r], *reinterpret_cast<const float4*>(ep + (size_t)r * D));

    __shared__ float lsum[NSEC * D];   // 10 KB
    __shared__ float lcnt[NSEC];
    for (int i = threadIdx.x; i < NSEC * D; i += 256) lsum[i] = 0.f;
    if (threadIdx.x < NSEC) lcnt[threadIdx.x] = 0.f;
    __syncthreads();

    for (int w = 0; w < 4; ++w) {
        if (wid == w) {
#pragma unroll
            for (int ss = 0; ss < NSEC; ++ss) {
                float* p = &lsum[ss * D + lane * 4];
                p[0] += acc[ss].x; p[1] += acc[ss].y; p[2] += acc[ss].z; p[3] += acc[ss].w;
                if (lane == 0) lcnt[ss] += cnt[ss];
            }
        }
        __syncthreads();
    }

#pragma unroll
    for (int ss = 0; ss < NSEC; ++ss)
        atomicAdd(&ws[WS_SUMS + ss * D + threadIdx.x], lsum[ss * D + threadIdx.x]);
    if (threadIdx.x < NSEC)
        atomicAdd(&ws[WS_CNT + threadIdx.x], lcnt[threadIdx.x]);
}

// PROBE + PREFETCH: pure stream over temb with k_sums' exact load pattern.
// Runs after k_sums (so semb can't evict temb from L3), before k_dist (which
// then reads L3-resident temb at the R8-measured 6.4 TB/s warm rate).
__global__ __launch_bounds__(256) void k_warm(const float* __restrict__ temb,
                                              float* __restrict__ dummy, int nrows) {
    const int lane = threadIdx.x & 63;
    const int wid  = threadIdx.x >> 6;
    const int gw   = blockIdx.x * 4 + wid;
    const int nw   = gridDim.x * 4;
    const float* tp = temb + (size_t)lane * 4;

    float ax = 0.f, ay = 0.f, az = 0.f, aw = 0.f;
    int r = gw;
    for (; r + 3 * nw < nrows; r += 4 * nw) {
        const float4 v0 = *reinterpret_cast<const float4*>(tp + (size_t)r * D);
        const float4 v1 = *reinterpret_cast<const float4*>(tp + (size_t)(r + nw) * D);
        const float4 v2 = *reinterpret_cast<const float4*>(tp + (size_t)(r + 2 * nw) * D);
        const float4 v3 = *reinterpret_cast<const float4*>(tp + (size_t)(r + 3 * nw) * D);
        ax += v0.x + v1.x + v2.x + v3.x;
        ay += v0.y + v1.y + v2.y + v3.y;
        az += v0.z + v1.z + v2.z + v3.z;
        aw += v0.w + v1.w + v2.w + v3.w;
    }
    for (; r < nrows; r += nw) {
        const float4 v = *reinterpret_cast<const float4*>(tp + (size_t)r * D);
        ax += v.x; ay += v.y; az += v.z; aw += v.w;
    }

    float a = ax + ay + az + aw;
#pragma unroll
    for (int off = 32; off >= 1; off >>= 1) a += __shfl_xor(a, off, 64);
    __shared__ float wsum[4];
    if (lane == 0) wsum[wid] = a;
    __syncthreads();
    if (threadIdx.x == 0)
        dummy[blockIdx.x] = wsum[0] + wsum[1] + wsum[2] + wsum[3];  // keep reads live
}

// R7's k_dist verbatim (proven 16 us/sweep on L3-warm temb in R8).
__global__ __launch_bounds__(1024, 4) void k_dist(const float* __restrict__ temb,
                                                  const float* __restrict__ tsl,
                                                  float* __restrict__ ws, int nrows) {
    __shared__ float lc[NSEC * D];
    for (int i = threadIdx.x; i < NSEC * D; i += 1024) {
        const int s = i >> 8;  // i / D
        lc[i] = ws[WS_SUMS + i] / ws[WS_CNT + s];
    }
    __syncthreads();

    const int lane = threadIdx.x & 63;
    const int wid  = threadIdx.x >> 6;            // 0..15
    const int gw   = blockIdx.x * 16 + wid;       // global wave id (4096 total)
    const int nw   = gridDim.x * 16;

    const float* tp = temb + (size_t)lane * 4;

    float wacc = 0.f;
    int r = gw;
    for (; r + 7 * nw < nrows; r += 8 * nw) {
        float  t[8];
        float4 v[8];
#pragma unroll
        for (int k = 0; k < 8; ++k) t[k] = tsl[r + k * nw];
#pragma unroll
        for (int k = 0; k < 8; ++k)
            v[k] = *reinterpret_cast<const float4*>(tp + (size_t)(r + k * nw) * D);

        float l[8];
#pragma unroll
        for (int k = 0; k < 8; ++k) {
            int s = (int)floorf(t[k] / SLICE);   // exact reference semantics
            s = s < 0 ? 0 : (s > NSEC - 1 ? NSEC - 1 : s);
            const float4 c = *reinterpret_cast<const float4*>(&lc[s * D + lane * 4]);
            const float dx = v[k].x - c.x + EPS;
            const float dy = v[k].y - c.y + EPS;
            const float dz = v[k].z - c.z + EPS;
            const float dw = v[k].w - c.w + EPS;
            l[k] = dx * dx + dy * dy + dz * dz + dw * dw;
        }

#pragma unroll
        for (int off = 32; off >= 1; off >>= 1) {
#pragma unroll
            for (int k = 0; k < 8; ++k) l[k] += __shfl_xor(l[k], off, 64);
        }
#pragma unroll
        for (int k = 0; k < 8; ++k) wacc += sqrtf(l[k]);   // all lanes, no divergence
    }
    for (; r < nrows; r += nw) {
        const float si = tsl[r];
        int s = (int)floorf(si / SLICE);
        s = s < 0 ? 0 : (s > NSEC - 1 ? NSEC - 1 : s);
        const float4 vv = *reinterpret_cast<const float4*>(tp + (size_t)r * D);
        const float4 c = *reinterpret_cast<const float4*>(&lc[s * D + lane * 4]);
        const float dx = vv.x - c.x + EPS;
        const float dy = vv.y - c.y + EPS;
        const float dz = vv.z - c.z + EPS;
        const float dw = vv.w - c.w + EPS;
        float loc = dx * dx + dy * dy + dz * dz + dw * dw;
#pragma unroll
        for (int off = 32; off >= 1; off >>= 1) loc += __shfl_xor(loc, off, 64);
        wacc += sqrtf(loc);
    }

    __shared__ float wsum[16];
    if (lane == 0) wsum[wid] = wacc;
    __syncthreads();
    if (threadIdx.x == 0) {
        float t = 0.f;
#pragma unroll
        for (int k = 0; k < 16; ++k) t += wsum[k];
        ws[WS_PART + blockIdx.x] = t;   // plain store, private slot
    }
}

__global__ __launch_bounds__(256) void k_final(const float* __restrict__ ws,
                                               float* __restrict__ out, float invN) {
    float v = ws[WS_PART + threadIdx.x];
#pragma unroll
    for (int off = 32; off >= 1; off >>= 1) v += __shfl_xor(v, off, 64);
    __shared__ float s4[4];
    if ((threadIdx.x & 63) == 0) s4[threadIdx.x >> 6] = v;
    __syncthreads();
    if (threadIdx.x == 0) out[0] = (s4[0] + s4[1] + s4[2] + s4[3]) * invN;
}

extern "C" void kernel_launch(void* const* d_in, const int* in_sizes, int n_in,
                              void* d_out, int out_size, void* d_ws, size_t ws_size,
                              hipStream_t stream) {
    const float* semb = (const float*)d_in[0];   // [nS, 256] f32
    const int*   ssec = (const int*)d_in[1];     // [nS] i32
    const float* temb = (const float*)d_in[2];   // [nT, 256] f32
    const float* tsl  = (const float*)d_in[3];   // [nT] f32
    float* ws  = (float*)d_ws;
    float* out = (float*)d_out;
    const int nS = in_sizes[1];
    const int nT = in_sizes[3];

    hipLaunchKernelGGL(k_zero, dim3((WS_ZERO_FLOATS + 255) / 256), dim3(256), 0, stream, ws);
    hipLaunchKernelGGL(k_sums, dim3(1024), dim3(256), 0, stream, semb, ssec, ws, nS);
    hipLaunchKernelGGL(k_warm, dim3(1024), dim3(256), 0, stream, temb, ws + WS_WARM, nT);
    hipLaunchKernelGGL(k_dist, dim3(DIST_BLOCKS), dim3(1024), 0, stream, temb, tsl, ws, nT);
    hipLaunchKernelGGL(k_final, dim3(1), dim3(256), 0, stream, ws, out, 1.0f / (float)nT);
}

// Round 12
// 105.552 us; speedup vs baseline: 1.0928x; 1.0928x over previous
//
#include <hip/hip_runtime.h>
#include <math.h>

#define D      256
#define NSEC   10
#define EPS    1e-6f
#define SLICE  0.1f

#define CCS    264              // cc row stride (floats), 16B-aligned, pad vs banks
#define PS     65               // p_lds row stride: bank = (row + i) % 32, conflict-free
#define GR     32               // rows per wave-group

// ws float layout
#define WS_SUMS 0                        // [0,2560)    per-sector sums
#define WS_CNT  (NSEC * D)               // [2560,2570) per-sector counts
#define WS_CC   (NSEC * D + NSEC)        // [2570,5210) cc[s][d] = EPS - center (stride 264)
#define WS_PART (WS_CC + NSEC * CCS)     // [5210,...)  per-block partials
#define WS_ZERO_FLOATS (NSEC * D + NSEC)

__global__ void k_zero(float* __restrict__ ws) {
    int i = blockIdx.x * blockDim.x + threadIdx.x;
    if (i < WS_ZERO_FLOATS) ws[i] = 0.f;
}

// ---- k_sums: unchanged (measured ~5.3 TB/s cold) ----
__global__ __launch_bounds__(256) void k_sums(const float* __restrict__ emb,
                                              const int* __restrict__ sec,
                                              float* __restrict__ ws, int nrows) {
    const int lane = threadIdx.x & 63;
    const int wid  = threadIdx.x >> 6;
    const int gw   = blockIdx.x * 4 + wid;
    const int nw   = gridDim.x * 4;

    float4 acc[NSEC];
    float  cnt[NSEC];
#pragma unroll
    for (int s = 0; s < NSEC; ++s) { acc[s] = make_float4(0.f, 0.f, 0.f, 0.f); cnt[s] = 0.f; }

    const float* ep = emb + (size_t)lane * 4;

    auto accum = [&](int sv, float4 v) {
        const int s = __builtin_amdgcn_readfirstlane(sv);
#pragma unroll
        for (int ss = 0; ss < NSEC; ++ss) {
            if (s == ss) {
                acc[ss].x += v.x; acc[ss].y += v.y; acc[ss].z += v.z; acc[ss].w += v.w;
                cnt[ss] += 1.f;
            }
        }
    };

    int r = gw;
    for (; r + 3 * nw < nrows; r += 4 * nw) {
        const int s0 = sec[r];
        const int s1 = sec[r + nw];
        const int s2 = sec[r + 2 * nw];
        const int s3 = sec[r + 3 * nw];
        const float4 v0 = *reinterpret_cast<const float4*>(ep + (size_t)r * D);
        const float4 v1 = *reinterpret_cast<const float4*>(ep + (size_t)(r + nw) * D);
        const float4 v2 = *reinterpret_cast<const float4*>(ep + (size_t)(r + 2 * nw) * D);
        const float4 v3 = *reinterpret_cast<const float4*>(ep + (size_t)(r + 3 * nw) * D);
        accum(s0, v0); accum(s1, v1); accum(s2, v2); accum(s3, v3);
    }
    for (; r < nrows; r += nw)
        accum(sec[r], *reinterpret_cast<const float4*>(ep + (size_t)r * D));

    __shared__ float lsum[NSEC * D];
    __shared__ float lcnt[NSEC];
    for (int i = threadIdx.x; i < NSEC * D; i += 256) lsum[i] = 0.f;
    if (threadIdx.x < NSEC) lcnt[threadIdx.x] = 0.f;
    __syncthreads();

    for (int w = 0; w < 4; ++w) {
        if (wid == w) {
#pragma unroll
            for (int ss = 0; ss < NSEC; ++ss) {
                float* p = &lsum[ss * D + lane * 4];
                p[0] += acc[ss].x; p[1] += acc[ss].y; p[2] += acc[ss].z; p[3] += acc[ss].w;
                if (lane == 0) lcnt[ss] += cnt[ss];
            }
        }
        __syncthreads();
    }

#pragma unroll
    for (int ss = 0; ss < NSEC; ++ss)
        atomicAdd(&ws[WS_SUMS + ss * D + threadIdx.x], lsum[ss * D + threadIdx.x]);
    if (threadIdx.x < NSEC)
        atomicAdd(&ws[WS_CNT + threadIdx.x], lcnt[threadIdx.x]);
}

// cc[s][d] = EPS - sums[s][d]/cnt[s]  (so dist term is t + cc), pad zeroed
__global__ __launch_bounds__(256) void k_cc(float* __restrict__ ws) {
    const int t = threadIdx.x;
    __shared__ float inv[NSEC];
    if (t < NSEC) inv[t] = 1.f / ws[WS_CNT + t];
    __syncthreads();
#pragma unroll
    for (int s = 0; s < NSEC; ++s)
        ws[WS_CC + s * CCS + t] = EPS - ws[WS_SUMS + s * D + t] * inv[s];
    if (t < CCS - D) {
#pragma unroll
        for (int s = 0; s < NSEC; ++s) ws[WS_CC + s * CCS + D + t] = 0.f;
    }
}

// k_dist3: k_warm-independent global loads; cross-lane work amortized 1/32 rows.
// Each wave owns 32 consecutive rows. Phase 1: 4x8-row double-buffered chunks,
// per-lane FMA partial -> wave-private LDS P[32][65] (no syncthreads, no shfl).
// Phase 2 (once per wave): transposed stride-65 reads + 6 shuffles + sqrt.
__global__ __launch_bounds__(256, 3) void k_dist3(const float* __restrict__ temb,
                                                  const float* __restrict__ tsl,
                                                  const float* __restrict__ ws,
                                                  float* __restrict__ part, int nrows) {
    __shared__ float cc[NSEC * CCS];        // 10.56 KB
    __shared__ float pl[4][GR * PS];        // 4 x 8.32 KB wave-private slabs
    __shared__ int   sid[4][GR];
    __shared__ float bsum[4];
    const int t = threadIdx.x, lane = t & 63, wid = t >> 6;

    for (int i = t; i < NSEC * CCS; i += 256) cc[i] = ws[WS_CC + i];

    const int gbase = (blockIdx.x * 4 + wid) * GR;

    if (lane < GR) {
        int rr = gbase + lane; if (rr >= nrows) rr = nrows - 1;
        const float si = tsl[rr];
        int s = (int)floorf(si / SLICE);    // exact reference semantics
        s = s < 0 ? 0 : (s > NSEC - 1 ? NSEC - 1 : s);
        sid[wid][lane] = s * CCS;
    }
    __syncthreads();                        // cc ready (sid is wave-local anyway)

    const float* tp = temb + (size_t)lane * 4;
    float* P = pl[wid];
    const int* SID = sid[wid];

    float4 va[8], vb[8];
    auto LOAD = [&](float4* v, int c) {     // 8 fully independent 16B loads
#pragma unroll
        for (int k = 0; k < 8; ++k) {
            int rr = gbase + c * 8 + k; if (rr >= nrows) rr = nrows - 1;
            v[k] = *reinterpret_cast<const float4*>(tp + (size_t)rr * D);
        }
    };
    auto COMP = [&](float4* v, int c) {
#pragma unroll
        for (int k = 0; k < 8; ++k) {
            const int row = c * 8 + k;
            const int so  = SID[row];       // broadcast LDS read
            const float4 c4 = *reinterpret_cast<const float4*>(&cc[so + lane * 4]);
            const float dx = v[k].x + c4.x;
            const float dy = v[k].y + c4.y;
            const float dz = v[k].z + c4.z;
            const float dw = v[k].w + c4.w;
            P[row * PS + lane] = dx * dx + dy * dy + dz * dz + dw * dw;
        }
    };
    LOAD(va, 0); LOAD(vb, 1); COMP(va, 0);
    LOAD(va, 2); COMP(vb, 1);
    LOAD(vb, 3); COMP(va, 2);
    COMP(vb, 3);

    // phase 2: transpose-read row partials (bank = (row+i)%32 -> conflict-free)
    const int row = lane & 31, half = lane >> 5;
    float a = 0.f;
    const float* Pr = &P[row * PS + half * 32];
#pragma unroll
    for (int i = 0; i < 32; ++i) a += Pr[i];
    a += __shfl_xor(a, 32, 64);             // combine the two 32-dim halves
    const int rr = gbase + row;
    float dsum = (rr < nrows && half == 0) ? sqrtf(a) : 0.f;
#pragma unroll
    for (int off = 16; off >= 1; off >>= 1) dsum += __shfl_xor(dsum, off, 64);

    if (lane == 0) bsum[wid] = dsum;
    __syncthreads();
    if (t == 0) part[blockIdx.x] = bsum[0] + bsum[1] + bsum[2] + bsum[3];
}

__global__ __launch_bounds__(1024) void k_final(const float* __restrict__ part,
                                                float* __restrict__ out,
                                                int nparts, float invN) {
    float v = 0.f;
    for (int i = threadIdx.x; i < nparts; i += 1024) v += part[i];
#pragma unroll
    for (int off = 32; off >= 1; off >>= 1) v += __shfl_xor(v, off, 64);
    __shared__ float s16[16];
    if ((threadIdx.x & 63) == 0) s16[threadIdx.x >> 6] = v;
    __syncthreads();
    if (threadIdx.x == 0) {
        float tot = 0.f;
#pragma unroll
        for (int k = 0; k < 16; ++k) tot += s16[k];
        out[0] = tot * invN;
    }
}

extern "C" void kernel_launch(void* const* d_in, const int* in_sizes, int n_in,
                              void* d_out, int out_size, void* d_ws, size_t ws_size,
                              hipStream_t stream) {
    const float* semb = (const float*)d_in[0];   // [nS, 256] f32
    const int*   ssec = (const int*)d_in[1];     // [nS] i32
    const float* temb = (const float*)d_in[2];   // [nT, 256] f32
    const float* tsl  = (const float*)d_in[3];   // [nT] f32
    float* ws  = (float*)d_ws;
    float* out = (float*)d_out;
    const int nS = in_sizes[1];
    const int nT = in_sizes[3];
    const int nb = (nT + 127) / 128;             // 782 for nT=100000

    hipLaunchKernelGGL(k_zero, dim3((WS_ZERO_FLOATS + 255) / 256), dim3(256), 0, stream, ws);
    hipLaunchKernelGGL(k_sums, dim3(1024), dim3(256), 0, stream, semb, ssec, ws, nS);
    hipLaunchKernelGGL(k_cc, dim3(1), dim3(256), 0, stream, ws);
    hipLaunchKernelGGL(k_dist3, dim3(nb), dim3(256), 0, stream,
                       temb, tsl, ws, ws + WS_PART, nT);
    hipLaunchKernelGGL(k_final, dim3(1), dim3(1024), 0, stream,
                       ws + WS_PART, out, nb, 1.0f / (float)nT);
}

// Round 13
// 103.003 us; speedup vs baseline: 1.1199x; 1.0247x over previous
//
#include <hip/hip_runtime.h>
#include <math.h>

#define D      256
#define NSEC   10
#define EPS    1e-6f
#define SLICE  0.1f

// ws float layout
#define WS_SUMS 0                      // [0,2560) per-sector sums
#define WS_CNT  (NSEC * D)             // [2560,2570) per-sector counts
#define WS_PART (NSEC * D + NSEC)      // [2570,3594) per-block distance partials (1024)
#define WS_ZERO_FLOATS (NSEC * D + NSEC)

__global__ void k_zero(float* __restrict__ ws) {
    int i = blockIdx.x * blockDim.x + threadIdx.x;
    if (i < WS_ZERO_FLOATS) ws[i] = 0.f;
}

// ---- k_sums: unchanged (measured ~5.3 TB/s cold) ----
__global__ __launch_bounds__(256) void k_sums(const float* __restrict__ emb,
                                              const int* __restrict__ sec,
                                              float* __restrict__ ws, int nrows) {
    const int lane = threadIdx.x & 63;
    const int wid  = threadIdx.x >> 6;
    const int gw   = blockIdx.x * 4 + wid;
    const int nw   = gridDim.x * 4;

    float4 acc[NSEC];
    float  cnt[NSEC];
#pragma unroll
    for (int s = 0; s < NSEC; ++s) { acc[s] = make_float4(0.f, 0.f, 0.f, 0.f); cnt[s] = 0.f; }

    const float* ep = emb + (size_t)lane * 4;

    auto accum = [&](int sv, float4 v) {
        const int s = __builtin_amdgcn_readfirstlane(sv);
#pragma unroll
        for (int ss = 0; ss < NSEC; ++ss) {
            if (s == ss) {
                acc[ss].x += v.x; acc[ss].y += v.y; acc[ss].z += v.z; acc[ss].w += v.w;
                cnt[ss] += 1.f;
            }
        }
    };

    int r = gw;
    for (; r + 3 * nw < nrows; r += 4 * nw) {
        const int s0 = sec[r];
        const int s1 = sec[r + nw];
        const int s2 = sec[r + 2 * nw];
        const int s3 = sec[r + 3 * nw];
        const float4 v0 = *reinterpret_cast<const float4*>(ep + (size_t)r * D);
        const float4 v1 = *reinterpret_cast<const float4*>(ep + (size_t)(r + nw) * D);
        const float4 v2 = *reinterpret_cast<const float4*>(ep + (size_t)(r + 2 * nw) * D);
        const float4 v3 = *reinterpret_cast<const float4*>(ep + (size_t)(r + 3 * nw) * D);
        accum(s0, v0); accum(s1, v1); accum(s2, v2); accum(s3, v3);
    }
    for (; r < nrows; r += nw)
        accum(sec[r], *reinterpret_cast<const float4*>(ep + (size_t)r * D));

    __shared__ float lsum[NSEC * D];
    __shared__ float lcnt[NSEC];
    for (int i = threadIdx.x; i < NSEC * D; i += 256) lsum[i] = 0.f;
    if (threadIdx.x < NSEC) lcnt[threadIdx.x] = 0.f;
    __syncthreads();

    for (int w = 0; w < 4; ++w) {
        if (wid == w) {
#pragma unroll
            for (int ss = 0; ss < NSEC; ++ss) {
                float* p = &lsum[ss * D + lane * 4];
                p[0] += acc[ss].x; p[1] += acc[ss].y; p[2] += acc[ss].z; p[3] += acc[ss].w;
                if (lane == 0) lcnt[ss] += cnt[ss];
            }
        }
        __syncthreads();
    }

#pragma unroll
    for (int ss = 0; ss < NSEC; ++ss)
        atomicAdd(&ws[WS_SUMS + ss * D + threadIdx.x], lsum[ss * D + threadIdx.x]);
    if (threadIdx.x < NSEC)
        atomicAdd(&ws[WS_CNT + threadIdx.x], lcnt[threadIdx.x]);
}

// k_dist4: R7 body + HARD LOAD/USE FENCE. The asm memory clobber makes it
// illegal for the compiler to sink any of the 16 batched loads below it,
// forcing all to issue before the first consumer (one vmcnt drain per batch).
__global__ __launch_bounds__(256, 4) void k_dist4(const float* __restrict__ temb,
                                                  const float* __restrict__ tsl,
                                                  const float* __restrict__ ws,
                                                  float* __restrict__ part, int nrows) {
    __shared__ float lc[NSEC * D];     // 10 KB: centers
    for (int i = threadIdx.x; i < NSEC * D; i += 256) {
        const int s = i >> 8;  // i / D
        lc[i] = ws[WS_SUMS + i] / ws[WS_CNT + s];
    }
    __syncthreads();

    const int lane = threadIdx.x & 63;
    const int wid  = threadIdx.x >> 6;
    const int gw   = blockIdx.x * 4 + wid;       // 4096 waves
    const int nw   = gridDim.x * 4;

    const float* tp = temb + (size_t)lane * 4;

    float wacc = 0.f;
    int r = gw;
    for (; r + 7 * nw < nrows; r += 8 * nw) {
        float  t[8];
        float4 v[8];
#pragma unroll
        for (int k = 0; k < 8; ++k) t[k] = tsl[r + k * nw];
#pragma unroll
        for (int k = 0; k < 8; ++k)
            v[k] = *reinterpret_cast<const float4*>(tp + (size_t)(r + k * nw) * D);

        asm volatile("" ::: "memory");   // loads may NOT sink past this point

        float l[8];
#pragma unroll
        for (int k = 0; k < 8; ++k) {
            int s = (int)floorf(t[k] / SLICE);   // exact reference semantics
            s = s < 0 ? 0 : (s > NSEC - 1 ? NSEC - 1 : s);
            const float4 c = *reinterpret_cast<const float4*>(&lc[s * D + lane * 4]);
            const float dx = v[k].x - c.x + EPS;
            const float dy = v[k].y - c.y + EPS;
            const float dz = v[k].z - c.z + EPS;
            const float dw = v[k].w - c.w + EPS;
            l[k] = dx * dx + dy * dy + dz * dz + dw * dw;
        }

        // stage-major shuffle reduce: 8 independent chains per latency window
#pragma unroll
        for (int off = 32; off >= 1; off >>= 1) {
#pragma unroll
            for (int k = 0; k < 8; ++k) l[k] += __shfl_xor(l[k], off, 64);
        }
#pragma unroll
        for (int k = 0; k < 8; ++k) wacc += sqrtf(l[k]);   // all lanes, no divergence
    }
    for (; r < nrows; r += nw) {
        const float si = tsl[r];
        int s = (int)floorf(si / SLICE);
        s = s < 0 ? 0 : (s > NSEC - 1 ? NSEC - 1 : s);
        const float4 vv = *reinterpret_cast<const float4*>(tp + (size_t)r * D);
        const float4 c = *reinterpret_cast<const float4*>(&lc[s * D + lane * 4]);
        const float dx = vv.x - c.x + EPS;
        const float dy = vv.y - c.y + EPS;
        const float dz = vv.z - c.z + EPS;
        const float dw = vv.w - c.w + EPS;
        float loc = dx * dx + dy * dy + dz * dz + dw * dw;
#pragma unroll
        for (int off = 32; off >= 1; off >>= 1) loc += __shfl_xor(loc, off, 64);
        wacc += sqrtf(loc);
    }

    __shared__ float wsum[4];
    if (lane == 0) wsum[wid] = wacc;
    __syncthreads();
    if (threadIdx.x == 0)
        part[blockIdx.x] = wsum[0] + wsum[1] + wsum[2] + wsum[3];  // plain store
}

__global__ __launch_bounds__(1024) void k_final(const float* __restrict__ part,
                                                float* __restrict__ out,
                                                int nparts, float invN) {
    float v = 0.f;
    for (int i = threadIdx.x; i < nparts; i += 1024) v += part[i];
#pragma unroll
    for (int off = 32; off >= 1; off >>= 1) v += __shfl_xor(v, off, 64);
    __shared__ float s16[16];
    if ((threadIdx.x & 63) == 0) s16[threadIdx.x >> 6] = v;
    __syncthreads();
    if (threadIdx.x == 0) {
        float tot = 0.f;
#pragma unroll
        for (int k = 0; k < 16; ++k) tot += s16[k];
        out[0] = tot * invN;
    }
}

extern "C" void kernel_launch(void* const* d_in, const int* in_sizes, int n_in,
                              void* d_out, int out_size, void* d_ws, size_t ws_size,
                              hipStream_t stream) {
    const float* semb = (const float*)d_in[0];   // [nS, 256] f32
    const int*   ssec = (const int*)d_in[1];     // [nS] i32
    const float* temb = (const float*)d_in[2];   // [nT, 256] f32
    const float* tsl  = (const float*)d_in[3];   // [nT] f32
    float* ws  = (float*)d_ws;
    float* out = (float*)d_out;
    const int nS = in_sizes[1];
    const int nT = in_sizes[3];

    hipLaunchKernelGGL(k_zero, dim3((WS_ZERO_FLOATS + 255) / 256), dim3(256), 0, stream, ws);
    hipLaunchKernelGGL(k_sums, dim3(1024), dim3(256), 0, stream, semb, ssec, ws, nS);
    hipLaunchKernelGGL(k_dist4, dim3(1024), dim3(256), 0, stream,
                       temb, tsl, ws, ws + WS_PART, nT);
    hipLaunchKernelGGL(k_final, dim3(1), dim3(1024), 0, stream,
                       ws + WS_PART, out, 1024, 1.0f / (float)nT);
}